// Round 2
// baseline (1392.844 us; speedup 1.0000x reference)
//
#include <hip/hip_runtime.h>
#include <hip/hip_bf16.h>

#define BB 2048
#define TT 2048
#define HH 16

// ---- helpers ----
__device__ __forceinline__ float bf2f(unsigned short u) {
    union { unsigned int i; float f; } v; v.i = ((unsigned int)u) << 16; return v.f;
}
__device__ __forceinline__ unsigned short f2bf(float f) {
    union { float f; unsigned int i; } v; v.f = f;
    unsigned int r = v.i + 0x7fffu + ((v.i >> 16) & 1u);  // RTNE
    return (unsigned short)(r >> 16);
}
__device__ __forceinline__ float rl(float v, int l) {
    return __int_as_float(__builtin_amdgcn_readlane(__float_as_int(v), l));
}
__device__ __forceinline__ float fexp2(float x) {
#if __has_builtin(__builtin_amdgcn_exp2f)
    return __builtin_amdgcn_exp2f(x);
#else
    return exp2f(x);
#endif
}
__device__ __forceinline__ float frcp(float x) {
#if __has_builtin(__builtin_amdgcn_rcpf)
    return __builtin_amdgcn_rcpf(x);
#else
    return 1.0f / x;
#endif
}

#define L2E  1.442695041f
#define L2E2 2.885390082f

// dtype probe: for bf16 data every u16 of W_hh0 decodes to |w|<=0.25;
// for fp32 data the random low mantissa halves decode huge/NaN -> flag=1 (fp32).
__global__ void detect_kernel(const unsigned short* __restrict__ w, int* __restrict__ flag) {
    if (threadIdx.x == 0 && blockIdx.x == 0) {
        int isf32 = 0;
        for (int i = 0; i < 64; ++i) {
            float v = bf2f(w[i]);
            if (!(v * v <= 1.0f)) isf32 = 1;   // NaN fails <= too
        }
        *flag = isf32;
    }
}

template <bool F32>
__device__ __forceinline__ float LD(const void* p, size_t i) {
    if constexpr (F32) return ((const float*)p)[i];
    else               return bf2f(((const unsigned short*)p)[i]);
}
template <bool F32>
__device__ __forceinline__ void ST(void* p, size_t i, float v) {
    if constexpr (F32) ((float*)p)[i] = v;
    else               ((unsigned short*)p)[i] = f2bf(v);
}

template <bool F32>
__global__ __launch_bounds__(256) void lstm2_kernel(
    const void* __restrict__ x,     // [B,T,1]
    const void* __restrict__ h0in,  // [2,B,16]
    const void* __restrict__ c0in,  // [2,B,16]
    const void* __restrict__ Wih0,  // [64,1]
    const void* __restrict__ Whh0,  // [64,16]
    const void* __restrict__ bih0,  // [64]
    const void* __restrict__ bhh0,  // [64]
    const void* __restrict__ Wih1,  // [64,16]
    const void* __restrict__ Whh1,  // [64,16]
    const void* __restrict__ bih1,  // [64]
    const void* __restrict__ bhh1,  // [64]
    void* __restrict__ out,         // [B*T*16] ++ hN[2,B,16] ++ cN[2,B,16]
    const int* __restrict__ flag)
{
    if ((*flag != 0) != F32) return;   // wrong-dtype instantiation: null launch

    const int lane = threadIdx.x & 63;
    const int wid  = threadIdx.x >> 6;
    const int b    = blockIdx.x * 4 + wid;    // one wave per batch row
    const int j    = lane & 15;               // hidden unit owned by this lane-group

    // per-lane weight rows (lane = gate row g in [0,64))
    float w0[16], wi1[16], w1[16];
#pragma unroll
    for (int k = 0; k < 16; ++k) {
        w0[k]  = LD<F32>(Whh0, lane * 16 + k);
        wi1[k] = LD<F32>(Wih1, lane * 16 + k);
        w1[k]  = LD<F32>(Whh1, lane * 16 + k);
    }
    const float wx    = LD<F32>(Wih0, lane);
    const float bias0 = LD<F32>(bih0, lane) + LD<F32>(bhh0, lane);
    const float bias1 = LD<F32>(bih1, lane) + LD<F32>(bhh1, lane);

    // recurrent state (lanes 0..15 authoritative; other lane-groups replicate)
    float h0 = LD<F32>(h0in, 0 * BB * HH + b * HH + j);
    float c0 = LD<F32>(c0in, 0 * BB * HH + b * HH + j);
    float h1 = LD<F32>(h0in, 1 * BB * HH + b * HH + j);
    float c1 = LD<F32>(c0in, 1 * BB * HH + b * HH + j);

    // lanes 0-31 (i,f): sigmoid; 32-47 (g): tanh; 48-63 (o): sigmoid
    const bool is_tanh = ((lane >> 4) == 2);
    const float Aa = is_tanh ? 2.0f  : 1.0f;
    const float Bb = is_tanh ? -L2E2 : -L2E;
    const float Cc = is_tanh ? -1.0f : 0.0f;

    const int src_f = j + 16, src_g = j + 32, src_o = j + 48;

    const size_t xbase   = (size_t)b * TT;
    const size_t outbase = (size_t)b * TT * HH;

    for (int t0 = 0; t0 < TT; t0 += 64) {
        // stage 64 timesteps of x per wave (coalesced), pre-normalized to f32 bits
        int xraw;
        if constexpr (F32) {
            xraw = __float_as_int(((const float*)x)[xbase + t0 + lane]);
        } else {
            xraw = ((int)((const unsigned short*)x)[xbase + t0 + lane]) << 16;
        }

#pragma unroll 4
        for (int tt = 0; tt < 64; ++tt) {
            float xt = __int_as_float(__builtin_amdgcn_readlane(xraw, tt));

            // ---- layer 0: g = x*Wih0[g] + bias + Whh0[g,:] @ h0 ----
            float acc = fmaf(xt, wx, bias0);
#pragma unroll
            for (int k = 0; k < 16; ++k) acc = fmaf(rl(h0, k), w0[k], acc);
            float act = fmaf(Aa, frcp(1.0f + fexp2(Bb * acc)), Cc);

            float f_ = __shfl(act, src_f, 64);
            float g_ = __shfl(act, src_g, 64);
            float o_ = __shfl(act, src_o, 64);
            float c0n = fmaf(f_, c0, act * g_);          // lanes 0..15 hold real c
            float tc0 = fmaf(2.0f, frcp(1.0f + fexp2(-L2E2 * c0n)), -1.0f);
            c0 = c0n;
            h0 = o_ * tc0;

            // ---- layer 1: g = bias + Wih1[g,:]@h0_new + Whh1[g,:]@h1 ----
            float acc1 = bias1;
#pragma unroll
            for (int k = 0; k < 16; ++k) acc1 = fmaf(rl(h0, k), wi1[k], acc1);
#pragma unroll
            for (int k = 0; k < 16; ++k) acc1 = fmaf(rl(h1, k), w1[k], acc1);
            float act1 = fmaf(Aa, frcp(1.0f + fexp2(Bb * acc1)), Cc);

            float f1 = __shfl(act1, src_f, 64);
            float g1 = __shfl(act1, src_g, 64);
            float o1 = __shfl(act1, src_o, 64);
            float c1n = fmaf(f1, c1, act1 * g1);
            float tc1 = fmaf(2.0f, frcp(1.0f + fexp2(-L2E2 * c1n)), -1.0f);
            c1 = c1n;
            h1 = o1 * tc1;

            if (lane < 16) ST<F32>(out, outbase + (size_t)(t0 + tt) * HH + lane, h1);
        }
    }

    // final states: hN = [h_layer0_T, h_layer1_T], cN likewise
    if (lane < 16) {
        const size_t offH = (size_t)BB * TT * HH;
        const size_t offC = offH + (size_t)2 * BB * HH;
        ST<F32>(out, offH + 0 * BB * HH + b * HH + lane, h0);
        ST<F32>(out, offH + 1 * BB * HH + b * HH + lane, h1);
        ST<F32>(out, offC + 0 * BB * HH + b * HH + lane, c0);
        ST<F32>(out, offC + 1 * BB * HH + b * HH + lane, c1);
    }
}

extern "C" void kernel_launch(void* const* d_in, const int* in_sizes, int n_in,
                              void* d_out, int out_size, void* d_ws, size_t ws_size,
                              hipStream_t stream) {
    const void* x    = d_in[0];
    const void* h0   = d_in[1];
    const void* c0   = d_in[2];
    const void* Wih0 = d_in[3];
    const void* Whh0 = d_in[4];
    const void* bih0 = d_in[5];
    const void* bhh0 = d_in[6];
    const void* Wih1 = d_in[7];
    const void* Whh1 = d_in[8];
    const void* bih1 = d_in[9];
    const void* bhh1 = d_in[10];
    int* flag = (int*)d_ws;

    detect_kernel<<<1, 64, 0, stream>>>((const unsigned short*)Whh0, flag);

    dim3 grid(BB / 4);   // 512 blocks x 4 waves = 2048 waves, one per batch row
    dim3 block(256);
    lstm2_kernel<false><<<grid, block, 0, stream>>>(x, h0, c0, Wih0, Whh0, bih0, bhh0,
                                                    Wih1, Whh1, bih1, bhh1, d_out, flag);
    lstm2_kernel<true ><<<grid, block, 0, stream>>>(x, h0, c0, Wih0, Whh0, bih0, bhh0,
                                                    Wih1, Whh1, bih1, bhh1, d_out, flag);
}

// Round 3
// 1195.930 us; speedup vs baseline: 1.1647x; 1.1647x over previous
//
#include <hip/hip_runtime.h>

#define BB 2048
#define TT 2048
#define HH 16

// ---- helpers ----
__device__ __forceinline__ float rl(float v, int l) {
    return __int_as_float(__builtin_amdgcn_readlane(__float_as_int(v), l));
}
__device__ __forceinline__ float bperm(int byteaddr, float v) {
    return __int_as_float(__builtin_amdgcn_ds_bpermute(byteaddr, __float_as_int(v)));
}
__device__ __forceinline__ float fexp2(float x) {
#if __has_builtin(__builtin_amdgcn_exp2f)
    return __builtin_amdgcn_exp2f(x);
#else
    return exp2f(x);
#endif
}
__device__ __forceinline__ float frcp(float x) {
#if __has_builtin(__builtin_amdgcn_rcpf)
    return __builtin_amdgcn_rcpf(x);
#else
    return 1.0f / x;
#endif
}

#define L2E  1.442695041f
#define L2E2 2.885390082f

// 1 wave = 1 batch row; lane = gate row g in [0,64); 2048 waves = 8 waves/CU.
// __launch_bounds__(256, 2): we only ever have 2 waves/EU -> give the register
// allocator the full 256-VGPR budget so the 48 weight floats stay resident.
__global__ __launch_bounds__(256, 2) void lstm2_kernel(
    const float* __restrict__ x,     // [B,T,1]
    const float* __restrict__ h0in,  // [2,B,16]
    const float* __restrict__ c0in,  // [2,B,16]
    const float* __restrict__ Wih0,  // [64,1]
    const float* __restrict__ Whh0,  // [64,16]
    const float* __restrict__ bih0,  // [64]
    const float* __restrict__ bhh0,  // [64]
    const float* __restrict__ Wih1,  // [64,16]
    const float* __restrict__ Whh1,  // [64,16]
    const float* __restrict__ bih1,  // [64]
    const float* __restrict__ bhh1,  // [64]
    float* __restrict__ out)         // [B*T*16] ++ hN[2,B,16] ++ cN[2,B,16]
{
    const int lane = threadIdx.x & 63;
    const int wid  = threadIdx.x >> 6;
    const int b    = blockIdx.x * 4 + wid;
    const int j    = lane & 15;

    // per-lane weight rows (lane = gate row)
    float w0[16], wi1[16], w1[16];
#pragma unroll
    for (int k = 0; k < 16; ++k) {
        w0[k]  = Whh0[lane * 16 + k];
        wi1[k] = Wih1[lane * 16 + k];
        w1[k]  = Whh1[lane * 16 + k];
    }
    const float wx    = Wih0[lane];
    const float bias0 = bih0[lane] + bhh0[lane];
    const float bias1 = bih1[lane] + bhh1[lane];

    // state, replicated across all 4 lane-groups (every lane holds unit j=lane&15)
    float h0 = h0in[0 * BB * HH + b * HH + j];
    float c0 = c0in[0 * BB * HH + b * HH + j];
    float h1 = h0in[1 * BB * HH + b * HH + j];
    float c1 = c0in[1 * BB * HH + b * HH + j];

    // wave-uniform broadcast copies of h0/h1 (live in SGPRs)
    float sh0[16], sh1[16];
#pragma unroll
    for (int k = 0; k < 16; ++k) { sh0[k] = rl(h0, k); sh1[k] = rl(h1, k); }

    // activation selector: rows 0-31 (i,f) sigmoid, 32-47 (g) tanh, 48-63 (o) sigmoid
    const bool is_tanh = ((lane >> 4) == 2);
    const float Aa = is_tanh ? 2.0f  : 1.0f;
    const float Bb = is_tanh ? -L2E2 : -L2E;
    const float Cc = is_tanh ? -1.0f : 0.0f;

    // bpermute byte addresses for gathering (i,f,g,o) of unit j into every lane
    const int ai = j * 4, af = ai + 64, ag = ai + 128, ao = ai + 192;

    // store-batching: lane-group q captures h1 at sub-step (tt&3)==q
    const int  phase   = lane >> 4;
    float hist = 0.0f;

    const float* xp = x + (size_t)b * TT;
    float*       po = out + (size_t)b * TT * HH;

    for (int t0 = 0; t0 < TT; t0 += 64) {
        int xraw = __float_as_int(xp[t0 + lane]);   // 64 timesteps staged per wave

#pragma unroll 4
        for (int tt = 0; tt < 64; ++tt) {
            float xt = __int_as_float(__builtin_amdgcn_readlane(xraw, tt));

            // ---- layer 0: g = x*Wih0 + bias + Whh0 @ h0  (sh0 = h0^{t-1}) ----
            float A0 = fmaf(xt, wx, bias0), A1 = 0.0f;
#pragma unroll
            for (int k = 0; k < 16; k += 2) {
                A0 = fmaf(sh0[k],     w0[k],     A0);
                A1 = fmaf(sh0[k + 1], w0[k + 1], A1);
            }
            float acc = A0 + A1;
            float act = fmaf(Aa, frcp(1.0f + fexp2(Bb * acc)), Cc);

            float i_ = bperm(ai, act);
            float f_ = bperm(af, act);
            float g_ = bperm(ag, act);
            float o_ = bperm(ao, act);
            c0 = fmaf(f_, c0, i_ * g_);
            float tc0 = fmaf(2.0f, frcp(1.0f + fexp2(-L2E2 * c0)), -1.0f);
            h0 = o_ * tc0;

            // refresh h0 broadcast (used by layer 1 now AND layer 0 next step)
#pragma unroll
            for (int k = 0; k < 16; ++k) sh0[k] = rl(h0, k);

            // ---- layer 1: g = bias + Wih1 @ h0_new + Whh1 @ h1 ----
            float B0 = bias1, B1 = 0.0f;
#pragma unroll
            for (int k = 0; k < 16; k += 2) {
                B0 = fmaf(sh0[k],     wi1[k],     B0);
                B1 = fmaf(sh0[k + 1], wi1[k + 1], B1);
            }
#pragma unroll
            for (int k = 0; k < 16; k += 2) {
                B0 = fmaf(sh1[k],     w1[k],     B0);
                B1 = fmaf(sh1[k + 1], w1[k + 1], B1);
            }
            float acc1 = B0 + B1;
            float act1 = fmaf(Aa, frcp(1.0f + fexp2(Bb * acc1)), Cc);

            float i1 = bperm(ai, act1);
            float f1 = bperm(af, act1);
            float g1 = bperm(ag, act1);
            float o1 = bperm(ao, act1);
            c1 = fmaf(f1, c1, i1 * g1);
            float tc1 = fmaf(2.0f, frcp(1.0f + fexp2(-L2E2 * c1)), -1.0f);
            h1 = o1 * tc1;

#pragma unroll
            for (int k = 0; k < 16; ++k) sh1[k] = rl(h1, k);

            // capture h1 for this lane-group's sub-step; store 4 steps coalesced
            hist = (phase == (tt & 3)) ? h1 : hist;
            if ((tt & 3) == 3) {
                // offset (t0+tt-3)*16 + (phase*16 + j) == (t0+tt-3)*16 + lane
                po[(size_t)(t0 + tt - 3) * HH + lane] = hist;
            }
        }
    }

    // final states: hN = [h_l0, h_l1], cN likewise (state replicated; group 0 writes)
    if (lane < 16) {
        const size_t offH = (size_t)BB * TT * HH;
        const size_t offC = offH + (size_t)2 * BB * HH;
        out[offH + 0 * BB * HH + b * HH + lane] = h0;
        out[offH + 1 * BB * HH + b * HH + lane] = h1;
        out[offC + 0 * BB * HH + b * HH + lane] = c0;
        out[offC + 1 * BB * HH + b * HH + lane] = c1;
    }
}

extern "C" void kernel_launch(void* const* d_in, const int* in_sizes, int n_in,
                              void* d_out, int out_size, void* d_ws, size_t ws_size,
                              hipStream_t stream) {
    const float* x    = (const float*)d_in[0];
    const float* h0   = (const float*)d_in[1];
    const float* c0   = (const float*)d_in[2];
    const float* Wih0 = (const float*)d_in[3];
    const float* Whh0 = (const float*)d_in[4];
    const float* bih0 = (const float*)d_in[5];
    const float* bhh0 = (const float*)d_in[6];
    const float* Wih1 = (const float*)d_in[7];
    const float* Whh1 = (const float*)d_in[8];
    const float* bih1 = (const float*)d_in[9];
    const float* bhh1 = (const float*)d_in[10];
    float* out = (float*)d_out;

    dim3 grid(BB / 4);   // 512 blocks x 4 waves = 2048 waves, one per batch row
    dim3 block(256);
    lstm2_kernel<<<grid, block, 0, stream>>>(x, h0, c0, Wih0, Whh0, bih0, bhh0,
                                             Wih1, Whh1, bih1, bhh1, out);
}